// Round 11
// baseline (291.517 us; speedup 1.0000x reference)
//
#include <hip/hip_runtime.h>
#include <hip/hip_bf16.h>

typedef unsigned short u16;
typedef __attribute__((ext_vector_type(8))) short bf16x8;
typedef __attribute__((ext_vector_type(4))) float f32x4;
typedef __attribute__((ext_vector_type(4))) unsigned short u16x4;

#define EMB 1024
#define SEQ 2048
#define NH 16
#define HD 64

// ws element offsets (bf16 elems)
#define OFF_WT   0u          // [3072][1024]  WqT|WkT|WvT (bf16)
#define OFF_WOT  3145728u    // [1024][1024]  WoT (bf16)
#define OFF_Q    4194304u    // [64][64][2048]  (bh, d, s)  Q^T, pre-scaled by 0.125*log2e
#define OFF_K    12582912u   // [64][2048][64]  (bh, s, d)
#define OFF_VT   20971520u   // [64][64][2048]  (bh, d, s)  V transposed
#define OFF_OC   29360128u   // [8192][1024]   attn output, concat layout
// Xb (x in bf16) lives in d_out until gemm_out overwrites it (stream-ordered).

#define QSCALE 0.1803368801111f   // 0.125 * log2(e)

// Explicit full drain: vmcnt(0) lgkmcnt(0) expcnt(0).  The compiler's own
// waitcnt insertion does NOT reliably drain LDS-DMA (global_load_lds) at a
// barrier when the staging was issued in a different block across the loop
// backedge (R6/R10 corruption).  Force it at the ISA level.
#define FULL_DRAIN() __builtin_amdgcn_s_waitcnt(0)

__device__ __forceinline__ u16 f2bf(float f) {
    unsigned int x; __builtin_memcpy(&x, &f, 4);
    unsigned int r = x + 0x7fffu + ((x >> 16) & 1u);   // RNE
    return (u16)(r >> 16);
}

#if defined(__has_builtin) && __has_builtin(__builtin_amdgcn_cvt_pk_bf16_f32)
typedef __attribute__((ext_vector_type(2))) __bf16 bfv2;
__device__ __forceinline__ unsigned int pkbf(float a, float b) {
    bfv2 v = __builtin_amdgcn_cvt_pk_bf16_f32(a, b);   // elem0 = a (low half)
    unsigned int u; __builtin_memcpy(&u, &v, 4); return u;
}
#else
__device__ __forceinline__ unsigned int pkbf(float a, float b) {
    return (unsigned)f2bf(a) | ((unsigned)f2bf(b) << 16);
}
#endif

// bare v_exp_f32 (no overflow/denorm guards; scores are |x| < ~30 << 126)
#if defined(__has_builtin) && __has_builtin(__builtin_amdgcn_exp2f)
__device__ __forceinline__ float exp2fast(float x) { return __builtin_amdgcn_exp2f(x); }
#else
__device__ __forceinline__ float exp2fast(float x) { return __builtin_exp2f(x); }
#endif

__device__ __forceinline__ void gld_lds16(const void* gsrc, void* ldst) {
    void* g = const_cast<void*>(gsrc);
    __builtin_amdgcn_global_load_lds((__attribute__((address_space(1))) void*)g,
                                     (__attribute__((address_space(3))) void*)ldst,
                                     16, 0, 0);
}

// ---------------------------------------------------------------------------
// Kernel 0: convert x (fp32) -> Xb (bf16), 4 elems/thread.
// ---------------------------------------------------------------------------
__global__ __launch_bounds__(256) void convert_x(
    const float* __restrict__ x, u16* __restrict__ xb)
{
    int i = (blockIdx.x * 256 + threadIdx.x) * 4;
    float4 v = *(const float4*)&x[i];
    uint2 o = { pkbf(v.x, v.y), pkbf(v.z, v.w) };
    *(uint2*)&xb[i] = o;
}

// ---------------------------------------------------------------------------
// Kernel 1: transpose the four 1024x1024 fp32 weights into ws as bf16.
// ---------------------------------------------------------------------------
__global__ __launch_bounds__(256) void transpose_w(
    const float* __restrict__ W0, const float* __restrict__ W1,
    const float* __restrict__ W2, const float* __restrict__ W3,
    u16* __restrict__ ws)
{
    __shared__ u16 tile[64 * 65];
    const float* src = blockIdx.z == 0 ? W0 : blockIdx.z == 1 ? W1 : blockIdx.z == 2 ? W2 : W3;
    u16* dst = ws + (blockIdx.z < 3 ? (unsigned)blockIdx.z * 1048576u : OFF_WOT);
    const int k0 = blockIdx.x * 64, n0 = blockIdx.y * 64;
    const int t = threadIdx.x;
    #pragma unroll
    for (int i = 0; i < 16; i++) {
        int idx = i * 256 + t; int r = idx >> 6, c = idx & 63;
        tile[c * 65 + r] = f2bf(src[(k0 + r) * EMB + n0 + c]);
    }
    __syncthreads();
    #pragma unroll
    for (int i = 0; i < 16; i++) {
        int idx = i * 256 + t; int r = idx >> 6, c = idx & 63;
        dst[(n0 + r) * EMB + k0 + c] = tile[r * 65 + c];
    }
}

// ---------------------------------------------------------------------------
// Kernel 2: fused QKV projection.  C[8192,3072] = Xb[8192,1024] @ WT^T (+bias)
// Pipelined K-loop with EXPLICIT drains:
//   [drain + barrier A: stage(kt) complete] -> frag reads ->
//   [drain + barrier B: all waves' reads retired] -> stage(kt+1) -> MFMA.
// ---------------------------------------------------------------------------
__global__ __launch_bounds__(256) void gemm_qkv(
    const u16* __restrict__ X, const u16* __restrict__ WT,
    const float* __restrict__ bq, const float* __restrict__ bk, const float* __restrict__ bv,
    u16* __restrict__ Qt, u16* __restrict__ Ko, u16* __restrict__ Vt)
{
    __shared__ u16 Al[128 * 32];
    __shared__ u16 Bl[128 * 32];
    const int t = threadIdx.x, lane = t & 63, w = t >> 6;
    const int quad = lane >> 4, l15 = lane & 15;
    const int wr = w >> 1, wc = w & 1;
    const int m0 = blockIdx.x * 128, n0 = blockIdx.y * 128;
    const f32x4 fzero = {0.f, 0.f, 0.f, 0.f};

    // hoisted staging addresses: chunks gA = t, gB = 256 + t
    const int gA = t, gB = 256 + t;
    const int rA = gA >> 2, scA = ((gA & 3) ^ ((rA >> 1) & 3)) * 8;
    const int rB = gB >> 2, scB = ((gB & 3) ^ ((rB >> 1) & 3)) * 8;
    const u16* xs0 = X  + (size_t)(m0 + rA) * EMB + scA;   // + kt*32
    const u16* xs1 = X  + (size_t)(m0 + rB) * EMB + scB;
    const u16* ws0 = WT + (size_t)(n0 + rA) * EMB + scA;
    const u16* ws1 = WT + (size_t)(n0 + rB) * EMB + scB;

    f32x4 acc[4][4];
    #pragma unroll
    for (int i = 0; i < 4; i++)
        #pragma unroll
        for (int j = 0; j < 4; j++) acc[i][j] = fzero;

    // stage tile 0
    gld_lds16(xs0, &Al[gA * 8]);
    gld_lds16(xs1, &Al[gB * 8]);
    gld_lds16(ws0, &Bl[gA * 8]);
    gld_lds16(ws1, &Bl[gB * 8]);

    for (int kt = 0; kt < 32; ++kt) {
        FULL_DRAIN();      // staging of kt complete (explicit vmcnt 0)
        __syncthreads();   // A
        bf16x8 af[4], bfr[4];
        #pragma unroll
        for (int i = 0; i < 4; i++) {
            int rowA = wr * 64 + i * 16 + l15;
            af[i] = *(const bf16x8*)&Al[rowA * 32 + ((quad ^ ((rowA >> 1) & 3)) * 8)];
        }
        #pragma unroll
        for (int j = 0; j < 4; j++) {
            int rowB = wc * 64 + j * 16 + l15;
            bfr[j] = *(const bf16x8*)&Bl[rowB * 32 + ((quad ^ ((rowB >> 1) & 3)) * 8)];
        }
        FULL_DRAIN();      // this wave's frag reads retired (explicit lgkm 0)
        __syncthreads();   // B
        if (kt + 1 < 32) {
            const int o = (kt + 1) * 32;
            gld_lds16(xs0 + o, &Al[gA * 8]);
            gld_lds16(xs1 + o, &Al[gB * 8]);
            gld_lds16(ws0 + o, &Bl[gA * 8]);
            gld_lds16(ws1 + o, &Bl[gB * 8]);
        }
        #pragma unroll
        for (int i = 0; i < 4; i++)
            #pragma unroll
            for (int j = 0; j < 4; j++)
                acc[i][j] = __builtin_amdgcn_mfma_f32_16x16x32_bf16(af[i], bfr[j], acc[i][j], 0, 0, 0);
    }

    const int seg = n0 >> 10;
    const float* bias = seg == 0 ? bq : (seg == 1 ? bk : bv);
    #pragma unroll
    for (int j = 0; j < 4; j++) {
        int n = n0 + wc * 64 + j * 16 + l15;
        int nn = n & 1023;
        float bvl = bias[nn];
        int h = nn >> 6, d = nn & 63;
        #pragma unroll
        for (int i = 0; i < 4; i++) {
            int m = m0 + wr * 64 + i * 16 + quad * 4;
            int b = m >> 11, s = m & 2047;
            if (seg == 0) {          // Q^T, scaled: [bh][d][s], s packed over regs
                uint2 pp = { pkbf((acc[i][j][0] + bvl) * QSCALE, (acc[i][j][1] + bvl) * QSCALE),
                             pkbf((acc[i][j][2] + bvl) * QSCALE, (acc[i][j][3] + bvl) * QSCALE) };
                *(uint2*)&Qt[(size_t)((b * NH + h) * HD + d) * SEQ + s] = pp;
            } else if (seg == 2) {   // V^T: [bh][d][s]
                uint2 pp = { pkbf(acc[i][j][0] + bvl, acc[i][j][1] + bvl),
                             pkbf(acc[i][j][2] + bvl, acc[i][j][3] + bvl) };
                *(uint2*)&Vt[(size_t)((b * NH + h) * HD + d) * SEQ + s] = pp;
            } else {                 // K: [bh][s][d]
                size_t base = (size_t)((b * NH + h) * SEQ + s) * HD + d;
                #pragma unroll
                for (int r = 0; r < 4; r++) Ko[base + (size_t)r * HD] = f2bf(acc[i][j][r] + bvl);
            }
        }
    }
}

// ---------------------------------------------------------------------------
// Kernel 3: flash attention, transposed-score + max-free softmax, 64 q/wave.
// Pipelined kt body with EXPLICIT drains (see gemm_qkv comment):
//   [drain+barrier A] -> all ak+av frag reads -> [drain+barrier B] ->
//   stage(kt+1) into same buffers -> softmax+PV compute hides the latency.
// ---------------------------------------------------------------------------
__global__ __launch_bounds__(256, 2) void flash_attn(
    const u16* __restrict__ Q, const u16* __restrict__ K,
    const u16* __restrict__ VT, u16* __restrict__ Oc)
{
    __shared__ u16 Kl[64 * 64];        // [key][d], chunk-swizzled
    __shared__ u16 Vl[64 * 64];        // [d][key], chunk-swizzled
    __shared__ u16 Pl[4 * 64 * 72];    // per-wave P^T [q_local 64][key 64], pad 72
    const int t = threadIdx.x, lane = t & 63, w = t >> 6;
    const int quad = lane >> 4, l15 = lane & 15;
    const int a7 = l15 & 7;
    const int bh = blockIdx.y;
    const int b = bh >> 4, h = bh & 15;
    const int q0 = blockIdx.x * 256 + w * 64;
    const u16* Qtb = Q + (size_t)bh * HD * SEQ;    // Q^T [d][s]
    const u16* Kb  = K + (size_t)bh * SEQ * HD;
    const u16* Vb  = VT + (size_t)bh * HD * SEQ;
    const f32x4 fzero = {0.f, 0.f, 0.f, 0.f};

    // hoisted staging addresses: chunks g0 = t, g1 = 256 + t
    const int g0 = t, g1 = 256 + t;
    const int r0 = g0 >> 3, sz0 = ((g0 & 7) ^ (r0 & 7)) * 8;
    const int r1 = g1 >> 3, sz1 = ((g1 & 7) ^ (r1 & 7)) * 8;
    const u16* ksrc0 = Kb + r0 * HD + sz0;          // + kt*4096
    const u16* ksrc1 = Kb + r1 * HD + sz1;
    const u16* vsrc0 = Vb + (size_t)r0 * SEQ + sz0; // + kt*64
    const u16* vsrc1 = Vb + (size_t)r1 * SEQ + sz1;

    // hoisted LDS fragment bases (f-invariant: (f*16+l15)&7 == l15&7)
    const u16* kbase0 = &Kl[l15 * 64 + ((quad ^ a7) * 8)];
    const u16* kbase1 = &Kl[l15 * 64 + (((4 + quad) ^ a7) * 8)];
    const u16* vbase0 = &Vl[l15 * 64 + ((quad ^ a7) * 8)];
    const u16* vbase1 = &Vl[l15 * 64 + (((4 + quad) ^ a7) * 8)];
    u16* Pw = &Pl[w * 64 * 72];
    u16* pww = Pw + l15 * 72 + quad * 4;         // write base (+ i*1152 + f*16)
    const u16* pwr = Pw + l15 * 72 + quad * 8;   // read base  (+ i*1152 + c*32)

    // constant all-ones A fragment (bf16 1.0 = 0x3F80)
    bf16x8 ones;
    #pragma unroll
    for (int j = 0; j < 8; j++) ones[j] = (short)0x3F80;

    // Q as B-operand fragments (persistent): B[k=d][n=q], n=l15, k=quad*8+j.
    bf16x8 qf[4][2];
    #pragma unroll
    for (int i = 0; i < 4; i++)
        #pragma unroll
        for (int c = 0; c < 2; c++)
            #pragma unroll
            for (int j = 0; j < 8; j++)
                qf[i][c][j] = (short)Qtb[(size_t)(c * 32 + quad * 8 + j) * SEQ + q0 + i * 16 + l15];

    f32x4 oacc[4][4];                  // [q-frag][d-frag], C: col=q, row=d
    f32x4 oextra[4];                   // ones.P^T -> every row = sum(p) for q=l15
    #pragma unroll
    for (int i = 0; i < 4; i++) {
        oextra[i] = fzero;
        #pragma unroll
        for (int f = 0; f < 4; f++) oacc[i][f] = fzero;
    }

    // stage tile 0
    gld_lds16(ksrc0, &Kl[g0 * 8]);
    gld_lds16(ksrc1, &Kl[g1 * 8]);
    gld_lds16(vsrc0, &Vl[g0 * 8]);
    gld_lds16(vsrc1, &Vl[g1 * 8]);

    for (int kt = 0; kt < 32; ++kt) {
        FULL_DRAIN();      // staging of kt complete (explicit vmcnt 0)
        __syncthreads();   // A

        // ALL K/V fragments for this tile, upfront (const-offset ds_read_b128)
        bf16x8 ak[2][4], av[2][4];
        #pragma unroll
        for (int f = 0; f < 4; f++) {
            ak[0][f] = *(const bf16x8*)(kbase0 + f * 1024);
            ak[1][f] = *(const bf16x8*)(kbase1 + f * 1024);
            av[0][f] = *(const bf16x8*)(vbase0 + f * 1024);
            av[1][f] = *(const bf16x8*)(vbase1 + f * 1024);
        }

        FULL_DRAIN();      // this wave's Kl/Vl reads retired (explicit lgkm 0)
        __syncthreads();   // B

        // stage kt+1 into the SAME buffers; latency hidden by compute below
        if (kt + 1 < 32) {
            const int ko = (kt + 1) * 4096;
            const int vo = (kt + 1) * 64;
            gld_lds16(ksrc0 + ko, &Kl[g0 * 8]);
            gld_lds16(ksrc1 + ko, &Kl[g1 * 8]);
            gld_lds16(vsrc0 + vo, &Vl[g0 * 8]);
            gld_lds16(vsrc1 + vo, &Vl[g1 * 8]);
        }

        // ---- phase 1: QK^T -> exp2 -> P writes ----
        #pragma unroll
        for (int i = 0; i < 4; i++) {
            f32x4 sf[4];
            #pragma unroll
            for (int f = 0; f < 4; f++) sf[f] = fzero;
            #pragma unroll
            for (int c = 0; c < 2; c++)
                #pragma unroll
                for (int f = 0; f < 4; f++)
                    sf[f] = __builtin_amdgcn_mfma_f32_16x16x32_bf16(ak[c][f], qf[i][c], sf[f], 0, 0, 0);
            #pragma unroll
            for (int f = 0; f < 4; f++) {
                float p0 = exp2fast(sf[f][0]);
                float p1 = exp2fast(sf[f][1]);
                float p2 = exp2fast(sf[f][2]);
                float p3 = exp2fast(sf[f][3]);
                uint2 pp = { pkbf(p0, p1), pkbf(p2, p3) };
                *(uint2*)(pww + i * 1152 + f * 16) = pp;
            }
        }

        // ---- phase 2: P readback -> PV + ones ----
        #pragma unroll
        for (int i = 0; i < 4; i++) {
            bf16x8 bp0 = *(const bf16x8*)(pwr + i * 1152);
            bf16x8 bp1 = *(const bf16x8*)(pwr + i * 1152 + 32);
            #pragma unroll
            for (int f = 0; f < 4; f++) {
                oacc[i][f] = __builtin_amdgcn_mfma_f32_16x16x32_bf16(av[0][f], bp0, oacc[i][f], 0, 0, 0);
                oacc[i][f] = __builtin_amdgcn_mfma_f32_16x16x32_bf16(av[1][f], bp1, oacc[i][f], 0, 0, 0);
            }
            oextra[i] = __builtin_amdgcn_mfma_f32_16x16x32_bf16(ones, bp0, oextra[i], 0, 0, 0);
            oextra[i] = __builtin_amdgcn_mfma_f32_16x16x32_bf16(ones, bp1, oextra[i], 0, 0, 0);
        }
    }

    // epilogue: O^T C-layout -> Oc[b][s][h][d]; d contiguous over regs
    #pragma unroll
    for (int i = 0; i < 4; i++) {
        float inv = 1.0f / oextra[i][0];
        int s = q0 + i * 16 + l15;
        size_t base = ((size_t)(b * SEQ + s) * NH + h) * HD;
        #pragma unroll
        for (int f = 0; f < 4; f++) {
            uint2 o = { pkbf(oacc[i][f][0] * inv, oacc[i][f][1] * inv),
                        pkbf(oacc[i][f][2] * inv, oacc[i][f][3] * inv) };
            *(uint2*)&Oc[base + f * 16 + quad * 4] = o;
        }
    }
}

// ---------------------------------------------------------------------------
// Kernel 4: output projection.  out[8192,1024] = Oc @ WoT^T + bo  (fp32 out)
// Same pipelined K-loop as gemm_qkv (explicit drains).
// ---------------------------------------------------------------------------
__global__ __launch_bounds__(256) void gemm_out(
    const u16* __restrict__ A, const u16* __restrict__ WT,
    const float* __restrict__ bo, float* __restrict__ out)
{
    __shared__ u16 Al[128 * 32];
    __shared__ u16 Bl[128 * 32];
    const int t = threadIdx.x, lane = t & 63, w = t >> 6;
    const int quad = lane >> 4, l15 = lane & 15;
    const int wr = w >> 1, wc = w & 1;
    const int m0 = blockIdx.x * 128, n0 = blockIdx.y * 128;
    const f32x4 fzero = {0.f, 0.f, 0.f, 0.f};

    const int gA = t, gB = 256 + t;
    const int rA = gA >> 2, scA = ((gA & 3) ^ ((rA >> 1) & 3)) * 8;
    const int rB = gB >> 2, scB = ((gB & 3) ^ ((rB >> 1) & 3)) * 8;
    const u16* as0 = A  + (size_t)(m0 + rA) * EMB + scA;
    const u16* as1 = A  + (size_t)(m0 + rB) * EMB + scB;
    const u16* bs0 = WT + (size_t)(n0 + rA) * EMB + scA;
    const u16* bs1 = WT + (size_t)(n0 + rB) * EMB + scB;

    f32x4 acc[4][4];
    #pragma unroll
    for (int i = 0; i < 4; i++)
        #pragma unroll
        for (int j = 0; j < 4; j++) acc[i][j] = fzero;

    gld_lds16(as0, &Al[gA * 8]);
    gld_lds16(as1, &Al[gB * 8]);
    gld_lds16(bs0, &Bl[gA * 8]);
    gld_lds16(bs1, &Bl[gB * 8]);

    for (int kt = 0; kt < 32; ++kt) {
        FULL_DRAIN();      // staging of kt complete
        __syncthreads();   // A
        bf16x8 af[4], bfr[4];
        #pragma unroll
        for (int i = 0; i < 4; i++) {
            int rowA = wr * 64 + i * 16 + l15;
            af[i] = *(const bf16x8*)&Al[rowA * 32 + ((quad ^ ((rowA >> 1) & 3)) * 8)];
        }
        #pragma unroll
        for (int j = 0; j < 4; j++) {
            int rowB = wc * 64 + j * 16 + l15;
            bfr[j] = *(const bf16x8*)&Bl[rowB * 32 + ((quad ^ ((rowB >> 1) & 3)) * 8)];
        }
        FULL_DRAIN();      // reads retired
        __syncthreads();   // B
        if (kt + 1 < 32) {
            const int o = (kt + 1) * 32;
            gld_lds16(as0 + o, &Al[gA * 8]);
            gld_lds16(as1 + o, &Al[gB * 8]);
            gld_lds16(bs0 + o, &Bl[gA * 8]);
            gld_lds16(bs1 + o, &Bl[gB * 8]);
        }
        #pragma unroll
        for (int i = 0; i < 4; i++)
            #pragma unroll
            for (int j = 0; j < 4; j++)
                acc[i][j] = __builtin_amdgcn_mfma_f32_16x16x32_bf16(af[i], bfr[j], acc[i][j], 0, 0, 0);
    }

    #pragma unroll
    for (int j = 0; j < 4; j++) {
        int n = n0 + wc * 64 + j * 16 + l15;
        float bvl = bo[n];
        #pragma unroll
        for (int i = 0; i < 4; i++) {
            int m = m0 + wr * 64 + i * 16 + quad * 4;
            #pragma unroll
            for (int r = 0; r < 4; r++)
                out[(size_t)(m + r) * EMB + n] = acc[i][j][r] + bvl;
        }
    }
}

// ---------------------------------------------------------------------------
extern "C" void kernel_launch(void* const* d_in, const int* in_sizes, int n_in,
                              void* d_out, int out_size, void* d_ws, size_t ws_size,
                              hipStream_t stream)
{
    (void)in_sizes; (void)n_in; (void)out_size; (void)ws_size;
    const float* x  = (const float*)d_in[0];
    const float* Wq = (const float*)d_in[1];
    const float* bq = (const float*)d_in[2];
    const float* Wk = (const float*)d_in[3];
    const float* bk = (const float*)d_in[4];
    const float* Wv = (const float*)d_in[5];
    const float* bv = (const float*)d_in[6];
    const float* Wo = (const float*)d_in[7];
    const float* bo = (const float*)d_in[8];
    u16* ws = (u16*)d_ws;
    u16* Xb = (u16*)d_out;   // bf16 copy of x lives in d_out until gemm_out runs

    convert_x<<<dim3(8192), 256, 0, stream>>>(x, Xb);
    transpose_w<<<dim3(16, 16, 4), 256, 0, stream>>>(Wq, Wk, Wv, Wo, ws);
    gemm_qkv<<<dim3(64, 24), 256, 0, stream>>>(Xb, ws + OFF_WT, bq, bk, bv,
                                               ws + OFF_Q, ws + OFF_K, ws + OFF_VT);
    flash_attn<<<dim3(8, 64), 256, 0, stream>>>(ws + OFF_Q, ws + OFF_K,
                                                ws + OFF_VT, ws + OFF_OC);
    gemm_out<<<dim3(64, 8), 256, 0, stream>>>(ws + OFF_OC, ws + OFF_WOT, bo, (float*)d_out);
}

// Round 12
// 291.296 us; speedup vs baseline: 1.0008x; 1.0008x over previous
//
#include <hip/hip_runtime.h>
#include <hip/hip_bf16.h>

typedef unsigned short u16;
typedef __attribute__((ext_vector_type(8))) short bf16x8;
typedef __attribute__((ext_vector_type(4))) float f32x4;
typedef __attribute__((ext_vector_type(4))) unsigned short u16x4;

#define EMB 1024
#define SEQ 2048
#define NH 16
#define HD 64

// ws element offsets (bf16 elems)
#define OFF_WT   0u          // [3072][1024]  WqT|WkT|WvT (bf16)
#define OFF_WOT  3145728u    // [1024][1024]  WoT (bf16)
#define OFF_Q    4194304u    // [64][64][2048]  (bh, d, s)  Q^T, pre-scaled by 0.125*log2e
#define OFF_K    12582912u   // [64][2048][64]  (bh, s, d)
#define OFF_VT   20971520u   // [64][64][2048]  (bh, d, s)  V transposed
#define OFF_OC   29360128u   // [8192][1024]   attn output, concat layout
// Xb (x in bf16) lives in d_out until gemm_out overwrites it (stream-ordered).

#define QSCALE 0.1803368801111f   // 0.125 * log2(e)

// Explicit full drain (vmcnt/lgkm/exp = 0).  Needed ONLY where staging is
// issued in a different basic block than the consuming barrier (flash's
// pipelined loop); R6/R10 showed compiler waitcnt insertion misses that case.
#define FULL_DRAIN() __builtin_amdgcn_s_waitcnt(0)

__device__ __forceinline__ u16 f2bf(float f) {
    unsigned int x; __builtin_memcpy(&x, &f, 4);
    unsigned int r = x + 0x7fffu + ((x >> 16) & 1u);   // RNE
    return (u16)(r >> 16);
}

#if defined(__has_builtin) && __has_builtin(__builtin_amdgcn_cvt_pk_bf16_f32)
typedef __attribute__((ext_vector_type(2))) __bf16 bfv2;
__device__ __forceinline__ unsigned int pkbf(float a, float b) {
    bfv2 v = __builtin_amdgcn_cvt_pk_bf16_f32(a, b);   // elem0 = a (low half)
    unsigned int u; __builtin_memcpy(&u, &v, 4); return u;
}
#else
__device__ __forceinline__ unsigned int pkbf(float a, float b) {
    return (unsigned)f2bf(a) | ((unsigned)f2bf(b) << 16);
}
#endif

// bare v_exp_f32 (no overflow/denorm guards; scores are |x| < ~30 << 126)
#if defined(__has_builtin) && __has_builtin(__builtin_amdgcn_exp2f)
__device__ __forceinline__ float exp2fast(float x) { return __builtin_amdgcn_exp2f(x); }
#else
__device__ __forceinline__ float exp2fast(float x) { return __builtin_exp2f(x); }
#endif

__device__ __forceinline__ void gld_lds16(const void* gsrc, void* ldst) {
    void* g = const_cast<void*>(gsrc);
    __builtin_amdgcn_global_load_lds((__attribute__((address_space(1))) void*)g,
                                     (__attribute__((address_space(3))) void*)ldst,
                                     16, 0, 0);
}

// ---------------------------------------------------------------------------
// Kernel 0: convert x (fp32) -> Xb (bf16), 4 elems/thread.
// ---------------------------------------------------------------------------
__global__ __launch_bounds__(256) void convert_x(
    const float* __restrict__ x, u16* __restrict__ xb)
{
    int i = (blockIdx.x * 256 + threadIdx.x) * 4;
    float4 v = *(const float4*)&x[i];
    uint2 o = { pkbf(v.x, v.y), pkbf(v.z, v.w) };
    *(uint2*)&xb[i] = o;
}

// ---------------------------------------------------------------------------
// Kernel 1: transpose the four 1024x1024 fp32 weights into ws as bf16.
// ---------------------------------------------------------------------------
__global__ __launch_bounds__(256) void transpose_w(
    const float* __restrict__ W0, const float* __restrict__ W1,
    const float* __restrict__ W2, const float* __restrict__ W3,
    u16* __restrict__ ws)
{
    __shared__ u16 tile[64 * 65];
    const float* src = blockIdx.z == 0 ? W0 : blockIdx.z == 1 ? W1 : blockIdx.z == 2 ? W2 : W3;
    u16* dst = ws + (blockIdx.z < 3 ? (unsigned)blockIdx.z * 1048576u : OFF_WOT);
    const int k0 = blockIdx.x * 64, n0 = blockIdx.y * 64;
    const int t = threadIdx.x;
    #pragma unroll
    for (int i = 0; i < 16; i++) {
        int idx = i * 256 + t; int r = idx >> 6, c = idx & 63;
        tile[c * 65 + r] = f2bf(src[(k0 + r) * EMB + n0 + c]);
    }
    __syncthreads();
    #pragma unroll
    for (int i = 0; i < 16; i++) {
        int idx = i * 256 + t; int r = idx >> 6, c = idx & 63;
        dst[(n0 + r) * EMB + k0 + c] = tile[r * 65 + c];
    }
}

// ---------------------------------------------------------------------------
// Kernel 2: fused QKV projection.  C[8192,3072] = Xb[8192,1024] @ WT^T (+bias)
// BK=64: 16 iterations, 32 MFMA per wave per barrier pair (2x amortization
// vs BK=32).  Two sequential k-chunks per iter so only one fragment set is
// live (VGPR stays at BK=32 level; LDS 32 KB).  Un-pipelined R9 semantics.
// ---------------------------------------------------------------------------
__global__ __launch_bounds__(256) void gemm_qkv(
    const u16* __restrict__ X, const u16* __restrict__ WT,
    const float* __restrict__ bq, const float* __restrict__ bk, const float* __restrict__ bv,
    u16* __restrict__ Qt, u16* __restrict__ Ko, u16* __restrict__ Vt)
{
    __shared__ u16 Al[128 * 64];
    __shared__ u16 Bl[128 * 64];
    const int t = threadIdx.x, lane = t & 63, w = t >> 6;
    const int quad = lane >> 4, l15 = lane & 15;
    const int a7 = l15 & 7;
    const int wr = w >> 1, wc = w & 1;
    const int m0 = blockIdx.x * 128, n0 = blockIdx.y * 128;
    const f32x4 fzero = {0.f, 0.f, 0.f, 0.f};

    // fragment bases: row = (wr|wc)*64 + i*16 + l15; k-chunk kc*4+quad XOR a7.
    // (f*16+l15)&7 == l15&7, so bases are i-invariant; i adds 16*64 elems.
    const u16* abase0 = &Al[(wr * 64 + l15) * 64 + ((quad ^ a7) * 8)];
    const u16* abase1 = &Al[(wr * 64 + l15) * 64 + (((4 + quad) ^ a7) * 8)];
    const u16* bbase0 = &Bl[(wc * 64 + l15) * 64 + ((quad ^ a7) * 8)];
    const u16* bbase1 = &Bl[(wc * 64 + l15) * 64 + (((4 + quad) ^ a7) * 8)];

    f32x4 acc[4][4];
    #pragma unroll
    for (int i = 0; i < 4; i++)
        #pragma unroll
        for (int j = 0; j < 4; j++) acc[i][j] = fzero;

    for (int kt = 0; kt < 16; ++kt) {
        // stage 128x64 of X and WT (same proven geometry as flash staging)
        #pragma unroll
        for (int r = 0; r < 4; r++) {
            int g = r * 256 + t; int row = g >> 3, cw = g & 7;
            int sc = (cw ^ (row & 7)) * 8;
            gld_lds16(X  + (size_t)(m0 + row) * EMB + kt * 64 + sc, &Al[g * 8]);
            gld_lds16(WT + (size_t)(n0 + row) * EMB + kt * 64 + sc, &Bl[g * 8]);
        }
        __syncthreads();
        // k-chunk 0
        {
            bf16x8 af[4], bfr[4];
            #pragma unroll
            for (int i = 0; i < 4; i++) af[i] = *(const bf16x8*)(abase0 + i * 1024);
            #pragma unroll
            for (int j = 0; j < 4; j++) bfr[j] = *(const bf16x8*)(bbase0 + j * 1024);
            #pragma unroll
            for (int i = 0; i < 4; i++)
                #pragma unroll
                for (int j = 0; j < 4; j++)
                    acc[i][j] = __builtin_amdgcn_mfma_f32_16x16x32_bf16(af[i], bfr[j], acc[i][j], 0, 0, 0);
        }
        // k-chunk 1
        {
            bf16x8 af[4], bfr[4];
            #pragma unroll
            for (int i = 0; i < 4; i++) af[i] = *(const bf16x8*)(abase1 + i * 1024);
            #pragma unroll
            for (int j = 0; j < 4; j++) bfr[j] = *(const bf16x8*)(bbase1 + j * 1024);
            #pragma unroll
            for (int i = 0; i < 4; i++)
                #pragma unroll
                for (int j = 0; j < 4; j++)
                    acc[i][j] = __builtin_amdgcn_mfma_f32_16x16x32_bf16(af[i], bfr[j], acc[i][j], 0, 0, 0);
        }
        __syncthreads();
    }

    const int seg = n0 >> 10;
    const float* bias = seg == 0 ? bq : (seg == 1 ? bk : bv);
    #pragma unroll
    for (int j = 0; j < 4; j++) {
        int n = n0 + wc * 64 + j * 16 + l15;
        int nn = n & 1023;
        float bvl = bias[nn];
        int h = nn >> 6, d = nn & 63;
        #pragma unroll
        for (int i = 0; i < 4; i++) {
            int m = m0 + wr * 64 + i * 16 + quad * 4;
            int b = m >> 11, s = m & 2047;
            if (seg == 0) {          // Q^T, scaled: [bh][d][s], s packed over regs
                uint2 pp = { pkbf((acc[i][j][0] + bvl) * QSCALE, (acc[i][j][1] + bvl) * QSCALE),
                             pkbf((acc[i][j][2] + bvl) * QSCALE, (acc[i][j][3] + bvl) * QSCALE) };
                *(uint2*)&Qt[(size_t)((b * NH + h) * HD + d) * SEQ + s] = pp;
            } else if (seg == 2) {   // V^T: [bh][d][s]
                uint2 pp = { pkbf(acc[i][j][0] + bvl, acc[i][j][1] + bvl),
                             pkbf(acc[i][j][2] + bvl, acc[i][j][3] + bvl) };
                *(uint2*)&Vt[(size_t)((b * NH + h) * HD + d) * SEQ + s] = pp;
            } else {                 // K: [bh][s][d]
                size_t base = (size_t)((b * NH + h) * SEQ + s) * HD + d;
                #pragma unroll
                for (int r = 0; r < 4; r++) Ko[base + (size_t)r * HD] = f2bf(acc[i][j][r] + bvl);
            }
        }
    }
}

// ---------------------------------------------------------------------------
// Kernel 3: flash attention (R11 form, unchanged): transposed-score +
// max-free softmax, 64 q/wave, pipelined staging with explicit drains.
// ---------------------------------------------------------------------------
__global__ __launch_bounds__(256, 2) void flash_attn(
    const u16* __restrict__ Q, const u16* __restrict__ K,
    const u16* __restrict__ VT, u16* __restrict__ Oc)
{
    __shared__ u16 Kl[64 * 64];        // [key][d], chunk-swizzled
    __shared__ u16 Vl[64 * 64];        // [d][key], chunk-swizzled
    __shared__ u16 Pl[4 * 64 * 72];    // per-wave P^T [q_local 64][key 64], pad 72
    const int t = threadIdx.x, lane = t & 63, w = t >> 6;
    const int quad = lane >> 4, l15 = lane & 15;
    const int a7 = l15 & 7;
    const int bh = blockIdx.y;
    const int b = bh >> 4, h = bh & 15;
    const int q0 = blockIdx.x * 256 + w * 64;
    const u16* Qtb = Q + (size_t)bh * HD * SEQ;    // Q^T [d][s]
    const u16* Kb  = K + (size_t)bh * SEQ * HD;
    const u16* Vb  = VT + (size_t)bh * HD * SEQ;
    const f32x4 fzero = {0.f, 0.f, 0.f, 0.f};

    // hoisted staging addresses: chunks g0 = t, g1 = 256 + t
    const int g0 = t, g1 = 256 + t;
    const int r0 = g0 >> 3, sz0 = ((g0 & 7) ^ (r0 & 7)) * 8;
    const int r1 = g1 >> 3, sz1 = ((g1 & 7) ^ (r1 & 7)) * 8;
    const u16* ksrc0 = Kb + r0 * HD + sz0;          // + kt*4096
    const u16* ksrc1 = Kb + r1 * HD + sz1;
    const u16* vsrc0 = Vb + (size_t)r0 * SEQ + sz0; // + kt*64
    const u16* vsrc1 = Vb + (size_t)r1 * SEQ + sz1;

    // hoisted LDS fragment bases (f-invariant: (f*16+l15)&7 == l15&7)
    const u16* kbase0 = &Kl[l15 * 64 + ((quad ^ a7) * 8)];
    const u16* kbase1 = &Kl[l15 * 64 + (((4 + quad) ^ a7) * 8)];
    const u16* vbase0 = &Vl[l15 * 64 + ((quad ^ a7) * 8)];
    const u16* vbase1 = &Vl[l15 * 64 + (((4 + quad) ^ a7) * 8)];
    u16* Pw = &Pl[w * 64 * 72];
    u16* pww = Pw + l15 * 72 + quad * 4;         // write base (+ i*1152 + f*16)
    const u16* pwr = Pw + l15 * 72 + quad * 8;   // read base  (+ i*1152 + c*32)

    // constant all-ones A fragment (bf16 1.0 = 0x3F80)
    bf16x8 ones;
    #pragma unroll
    for (int j = 0; j < 8; j++) ones[j] = (short)0x3F80;

    // Q as B-operand fragments (persistent): B[k=d][n=q], n=l15, k=quad*8+j.
    bf16x8 qf[4][2];
    #pragma unroll
    for (int i = 0; i < 4; i++)
        #pragma unroll
        for (int c = 0; c < 2; c++)
            #pragma unroll
            for (int j = 0; j < 8; j++)
                qf[i][c][j] = (short)Qtb[(size_t)(c * 32 + quad * 8 + j) * SEQ + q0 + i * 16 + l15];

    f32x4 oacc[4][4];                  // [q-frag][d-frag], C: col=q, row=d
    f32x4 oextra[4];                   // ones.P^T -> every row = sum(p) for q=l15
    #pragma unroll
    for (int i = 0; i < 4; i++) {
        oextra[i] = fzero;
        #pragma unroll
        for (int f = 0; f < 4; f++) oacc[i][f] = fzero;
    }

    // stage tile 0
    gld_lds16(ksrc0, &Kl[g0 * 8]);
    gld_lds16(ksrc1, &Kl[g1 * 8]);
    gld_lds16(vsrc0, &Vl[g0 * 8]);
    gld_lds16(vsrc1, &Vl[g1 * 8]);

    for (int kt = 0; kt < 32; ++kt) {
        FULL_DRAIN();      // staging of kt complete (explicit vmcnt 0)
        __syncthreads();   // A

        // ALL K/V fragments for this tile, upfront (const-offset ds_read_b128)
        bf16x8 ak[2][4], av[2][4];
        #pragma unroll
        for (int f = 0; f < 4; f++) {
            ak[0][f] = *(const bf16x8*)(kbase0 + f * 1024);
            ak[1][f] = *(const bf16x8*)(kbase1 + f * 1024);
            av[0][f] = *(const bf16x8*)(vbase0 + f * 1024);
            av[1][f] = *(const bf16x8*)(vbase1 + f * 1024);
        }

        FULL_DRAIN();      // this wave's Kl/Vl reads retired (explicit lgkm 0)
        __syncthreads();   // B

        // stage kt+1 into the SAME buffers; latency hidden by compute below
        if (kt + 1 < 32) {
            const int ko = (kt + 1) * 4096;
            const int vo = (kt + 1) * 64;
            gld_lds16(ksrc0 + ko, &Kl[g0 * 8]);
            gld_lds16(ksrc1 + ko, &Kl[g1 * 8]);
            gld_lds16(vsrc0 + vo, &Vl[g0 * 8]);
            gld_lds16(vsrc1 + vo, &Vl[g1 * 8]);
        }

        // ---- phase 1: QK^T -> exp2 -> P writes ----
        #pragma unroll
        for (int i = 0; i < 4; i++) {
            f32x4 sf[4];
            #pragma unroll
            for (int f = 0; f < 4; f++) sf[f] = fzero;
            #pragma unroll
            for (int c = 0; c < 2; c++)
                #pragma unroll
                for (int f = 0; f < 4; f++)
                    sf[f] = __builtin_amdgcn_mfma_f32_16x16x32_bf16(ak[c][f], qf[i][c], sf[f], 0, 0, 0);
            #pragma unroll
            for (int f = 0; f < 4; f++) {
                float p0 = exp2fast(sf[f][0]);
                float p1 = exp2fast(sf[f][1]);
                float p2 = exp2fast(sf[f][2]);
                float p3 = exp2fast(sf[f][3]);
                uint2 pp = { pkbf(p0, p1), pkbf(p2, p3) };
                *(uint2*)(pww + i * 1152 + f * 16) = pp;
            }
        }

        // ---- phase 2: P readback -> PV + ones ----
        #pragma unroll
        for (int i = 0; i < 4; i++) {
            bf16x8 bp0 = *(const bf16x8*)(pwr + i * 1152);
            bf16x8 bp1 = *(const bf16x8*)(pwr + i * 1152 + 32);
            #pragma unroll
            for (int f = 0; f < 4; f++) {
                oacc[i][f] = __builtin_amdgcn_mfma_f32_16x16x32_bf16(av[0][f], bp0, oacc[i][f], 0, 0, 0);
                oacc[i][f] = __builtin_amdgcn_mfma_f32_16x16x32_bf16(av[1][f], bp1, oacc[i][f], 0, 0, 0);
            }
            oextra[i] = __builtin_amdgcn_mfma_f32_16x16x32_bf16(ones, bp0, oextra[i], 0, 0, 0);
            oextra[i] = __builtin_amdgcn_mfma_f32_16x16x32_bf16(ones, bp1, oextra[i], 0, 0, 0);
        }
    }

    // epilogue: O^T C-layout -> Oc[b][s][h][d]; d contiguous over regs
    #pragma unroll
    for (int i = 0; i < 4; i++) {
        float inv = 1.0f / oextra[i][0];
        int s = q0 + i * 16 + l15;
        size_t base = ((size_t)(b * SEQ + s) * NH + h) * HD;
        #pragma unroll
        for (int f = 0; f < 4; f++) {
            uint2 o = { pkbf(oacc[i][f][0] * inv, oacc[i][f][1] * inv),
                        pkbf(oacc[i][f][2] * inv, oacc[i][f][3] * inv) };
            *(uint2*)&Oc[base + f * 16 + quad * 4] = o;
        }
    }
}

// ---------------------------------------------------------------------------
// Kernel 4: output projection.  out[8192,1024] = Oc @ WoT^T + bo  (fp32 out)
// Same BK=64 K-loop as gemm_qkv.
// ---------------------------------------------------------------------------
__global__ __launch_bounds__(256) void gemm_out(
    const u16* __restrict__ A, const u16* __restrict__ WT,
    const float* __restrict__ bo, float* __restrict__ out)
{
    __shared__ u16 Al[128 * 64];
    __shared__ u16 Bl[128 * 64];
    const int t = threadIdx.x, lane = t & 63, w = t >> 6;
    const int quad = lane >> 4, l15 = lane & 15;
    const int a7 = l15 & 7;
    const int wr = w >> 1, wc = w & 1;
    const int m0 = blockIdx.x * 128, n0 = blockIdx.y * 128;
    const f32x4 fzero = {0.f, 0.f, 0.f, 0.f};

    const u16* abase0 = &Al[(wr * 64 + l15) * 64 + ((quad ^ a7) * 8)];
    const u16* abase1 = &Al[(wr * 64 + l15) * 64 + (((4 + quad) ^ a7) * 8)];
    const u16* bbase0 = &Bl[(wc * 64 + l15) * 64 + ((quad ^ a7) * 8)];
    const u16* bbase1 = &Bl[(wc * 64 + l15) * 64 + (((4 + quad) ^ a7) * 8)];

    f32x4 acc[4][4];
    #pragma unroll
    for (int i = 0; i < 4; i++)
        #pragma unroll
        for (int j = 0; j < 4; j++) acc[i][j] = fzero;

    for (int kt = 0; kt < 16; ++kt) {
        #pragma unroll
        for (int r = 0; r < 4; r++) {
            int g = r * 256 + t; int row = g >> 3, cw = g & 7;
            int sc = (cw ^ (row & 7)) * 8;
            gld_lds16(A  + (size_t)(m0 + row) * EMB + kt * 64 + sc, &Al[g * 8]);
            gld_lds16(WT + (size_t)(n0 + row) * EMB + kt * 64 + sc, &Bl[g * 8]);
        }
        __syncthreads();
        {
            bf16x8 af[4], bfr[4];
            #pragma unroll
            for (int i = 0; i < 4; i++) af[i] = *(const bf16x8*)(abase0 + i * 1024);
            #pragma unroll
            for (int j = 0; j < 4; j++) bfr[j] = *(const bf16x8*)(bbase0 + j * 1024);
            #pragma unroll
            for (int i = 0; i < 4; i++)
                #pragma unroll
                for (int j = 0; j < 4; j++)
                    acc[i][j] = __builtin_amdgcn_mfma_f32_16x16x32_bf16(af[i], bfr[j], acc[i][j], 0, 0, 0);
        }
        {
            bf16x8 af[4], bfr[4];
            #pragma unroll
            for (int i = 0; i < 4; i++) af[i] = *(const bf16x8*)(abase1 + i * 1024);
            #pragma unroll
            for (int j = 0; j < 4; j++) bfr[j] = *(const bf16x8*)(bbase1 + j * 1024);
            #pragma unroll
            for (int i = 0; i < 4; i++)
                #pragma unroll
                for (int j = 0; j < 4; j++)
                    acc[i][j] = __builtin_amdgcn_mfma_f32_16x16x32_bf16(af[i], bfr[j], acc[i][j], 0, 0, 0);
        }
        __syncthreads();
    }

    #pragma unroll
    for (int j = 0; j < 4; j++) {
        int n = n0 + wc * 64 + j * 16 + l15;
        float bvl = bo[n];
        #pragma unroll
        for (int i = 0; i < 4; i++) {
            int m = m0 + wr * 64 + i * 16 + quad * 4;
            #pragma unroll
            for (int r = 0; r < 4; r++)
                out[(size_t)(m + r) * EMB + n] = acc[i][j][r] + bvl;
        }
    }
}

// ---------------------------------------------------------------------------
extern "C" void kernel_launch(void* const* d_in, const int* in_sizes, int n_in,
                              void* d_out, int out_size, void* d_ws, size_t ws_size,
                              hipStream_t stream)
{
    (void)in_sizes; (void)n_in; (void)out_size; (void)ws_size;
    const float* x  = (const float*)d_in[0];
    const float* Wq = (const float*)d_in[1];
    const float* bq = (const float*)d_in[2];
    const float* Wk = (const float*)d_in[3];
    const float* bk = (const float*)d_in[4];
    const float* Wv = (const float*)d_in[5];
    const float* bv = (const float*)d_in[6];
    const float* Wo = (const float*)d_in[7];
    const float* bo = (const float*)d_in[8];
    u16* ws = (u16*)d_ws;
    u16* Xb = (u16*)d_out;   // bf16 copy of x lives in d_out until gemm_out runs

    convert_x<<<dim3(8192), 256, 0, stream>>>(x, Xb);
    transpose_w<<<dim3(16, 16, 4), 256, 0, stream>>>(Wq, Wk, Wv, Wo, ws);
    gemm_qkv<<<dim3(64, 24), 256, 0, stream>>>(Xb, ws + OFF_WT, bq, bk, bv,
                                               ws + OFF_Q, ws + OFF_K, ws + OFF_VT);
    flash_attn<<<dim3(8, 64), 256, 0, stream>>>(ws + OFF_Q, ws + OFF_K,
                                                ws + OFF_VT, ws + OFF_OC);
    gemm_out<<<dim3(64, 8), 256, 0, stream>>>(ws + OFF_OC, ws + OFF_WOT, bo, (float*)d_out);
}